// Round 1
// baseline (750.947 us; speedup 1.0000x reference)
//
#include <hip/hip_runtime.h>

#define CI 64
#define CO 128
#define HH 64
#define WW 64
#define OH 62
#define OW 62
#define TH 8      // output rows per block
#define TW 32     // output cols per block
#define COB 32    // c_out per block
#define LDS_XW 36 // padded LDS row stride (34 cols used)

__global__ __launch_bounds__(256, 4)
void conv3x3_direct(const float* __restrict__ x, const float* __restrict__ wgt,
                    const float* __restrict__ bias, float* __restrict__ out) {
    __shared__ float xs[10][LDS_XW];
    __shared__ float ws[9][COB];

    const int tid = threadIdx.x;
    // grid: x = 16 spatial tiles (2 col x 8 row), y = 4 cout groups, z = batch
    const int tile  = blockIdx.x;
    const int ctile = tile & 1;   // 0..1
    const int rtile = tile >> 1;  // 0..7
    const int oh0 = rtile * TH;
    const int ow0 = ctile * TW;
    const int co0 = blockIdx.y * COB;
    const int b   = blockIdx.z;

    // thread mapping: 8 cout-subgroups x 32 pixel-groups
    const int co_grp = tid >> 5;      // 0..7 -> couts co_grp*4 .. +3
    const int pix    = tid & 31;      // 0..31
    const int prow   = pix >> 2;      // 0..7
    const int pcol   = (pix & 3) * 8; // 0,8,16,24

    float acc[4][8];
    #pragma unroll
    for (int i = 0; i < 4; ++i)
        #pragma unroll
        for (int j = 0; j < 8; ++j) acc[i][j] = 0.f;

    const float* xb = x + (size_t)b * CI * HH * WW;

    for (int ci = 0; ci < CI; ++ci) {
        __syncthreads();
        // stage x tile: input rows oh0..oh0+9, cols ow0..ow0+33 (zero-fill OOB)
        const float* xc = xb + ci * HH * WW;
        for (int i = tid; i < 340; i += 256) {
            int r = i / 34;
            int c = i - r * 34;
            int ih = oh0 + r, iw = ow0 + c;
            float v = 0.f;
            if (ih < HH && iw < WW) v = xc[ih * WW + iw];
            xs[r][c] = v;
        }
        // stage weights: layout [k][co] so loads are dense in co
        for (int i = tid; i < 288; i += 256) {
            int k  = i >> 5;
            int co = i & 31;
            ws[k][co] = wgt[((size_t)(co0 + co) * CI + ci) * 9 + k];
        }
        __syncthreads();

        // LDS -> registers: 3 rows x 10 cols of x (float4-aligned)
        float xr[3][10];
        #pragma unroll
        for (int r = 0; r < 3; ++r) {
            const float* src = &xs[prow + r][pcol];
            float4 a  = *(const float4*)(src);
            float4 bq = *(const float4*)(src + 4);
            float2 cq = *(const float2*)(src + 8);
            xr[r][0] = a.x;  xr[r][1] = a.y;  xr[r][2] = a.z;  xr[r][3] = a.w;
            xr[r][4] = bq.x; xr[r][5] = bq.y; xr[r][6] = bq.z; xr[r][7] = bq.w;
            xr[r][8] = cq.x; xr[r][9] = cq.y;
        }
        #pragma unroll
        for (int co = 0; co < 4; ++co) {
            float wv[9];
            #pragma unroll
            for (int k = 0; k < 9; ++k) wv[k] = ws[k][co_grp * 4 + co];
            #pragma unroll
            for (int p = 0; p < 8; ++p) {
                float s = acc[co][p];
                #pragma unroll
                for (int kr = 0; kr < 3; ++kr)
                    #pragma unroll
                    for (int kc = 0; kc < 3; ++kc)
                        s = fmaf(wv[kr * 3 + kc], xr[kr][p + kc], s);
                acc[co][p] = s;
            }
        }
    }

    // epilogue: add bias, guarded stores
    const int oh = oh0 + prow;
    if (oh < OH) {
        #pragma unroll
        for (int co = 0; co < 4; ++co) {
            const int cog = co0 + co_grp * 4 + co;
            const float bv = bias[cog];
            float* o = out + (((size_t)b * CO + cog) * OH + oh) * OW;
            #pragma unroll
            for (int p = 0; p < 8; ++p) {
                int ow = ow0 + pcol + p;
                if (ow < OW) o[ow] = acc[co][p] + bv;
            }
        }
    }
}

extern "C" void kernel_launch(void* const* d_in, const int* in_sizes, int n_in,
                              void* d_out, int out_size, void* d_ws, size_t ws_size,
                              hipStream_t stream) {
    const float* x    = (const float*)d_in[0];
    const float* wgt  = (const float*)d_in[1];
    const float* bias = (const float*)d_in[2];
    float* out = (float*)d_out;

    dim3 grid(16, CO / COB, 64); // 16 spatial tiles, 4 cout groups, 64 batches
    dim3 block(256);
    conv3x3_direct<<<grid, block, 0, stream>>>(x, wgt, bias, out);
}

// Round 2
// 290.025 us; speedup vs baseline: 2.5892x; 2.5892x over previous
//
#include <hip/hip_runtime.h>

#define CI 64
#define CO 128
#define HH 64
#define WW 64
#define OH 62
#define OW 62

typedef __attribute__((ext_vector_type(8))) short short8x;
typedef __attribute__((ext_vector_type(16))) float f32x16;

__device__ __forceinline__ ushort bf16rne(float f) {
    unsigned u = __builtin_bit_cast(unsigned, f);
    u += 0x7fffu + ((u >> 16) & 1u);
    return (ushort)(u >> 16);
}

// ---------------- prepass 1: X NCHW fp32 -> NHWC bf16 ----------------
__global__ __launch_bounds__(256)
void xpose(const float* __restrict__ x, ushort* __restrict__ xn) {
    __shared__ float t[64][65];
    const int b = blockIdx.y, h = blockIdx.x;
    const int tid = threadIdx.x;
    {
        const int ci = tid >> 2, w0 = (tid & 3) * 16;
        const float4* src = (const float4*)(x + (((b * 64 + ci) * 64) + h) * 64 + w0);
        #pragma unroll
        for (int i = 0; i < 4; ++i) {
            float4 v = src[i];
            t[ci][w0 + i * 4 + 0] = v.x;
            t[ci][w0 + i * 4 + 1] = v.y;
            t[ci][w0 + i * 4 + 2] = v.z;
            t[ci][w0 + i * 4 + 3] = v.w;
        }
    }
    __syncthreads();
    {
        const int w = tid >> 2, cg = (tid & 3) * 16;
        ushort o[16];
        #pragma unroll
        for (int j = 0; j < 16; ++j) o[j] = bf16rne(t[cg + j][w]);
        ushort* dst = xn + (((b * 64 + h) * 64 + w) * 64 + cg);
        *(uint4*)(dst)     = *(const uint4*)(&o[0]);
        *(uint4*)(dst + 8) = *(const uint4*)(&o[8]);
    }
}

// ---------------- prepass 2: W OIHW fp32 -> [k][co][ci] bf16 ----------------
__global__ __launch_bounds__(256)
void wprep(const float* __restrict__ w, ushort* __restrict__ wt) {
    const int idx = blockIdx.x * 256 + threadIdx.x;   // 73728 total
    const int kk = idx >> 13;          // /8192
    const int rem = idx & 8191;
    const int co = rem >> 6, ci = rem & 63;
    wt[idx] = bf16rne(w[(co * 64 + ci) * 9 + kk]);
}

// ---------------- main: implicit GEMM, 128co x 128px per block ----------------
// LDS rows: 64 ushorts, chunk i (8 ushorts) stored at position (i ^ (row&7)) -> 16B-aligned, conflict-free
__global__ __launch_bounds__(256, 3)
void conv_mfma(const ushort* __restrict__ xn, const ushort* __restrict__ wt,
               const float* __restrict__ bias, float* __restrict__ out) {
    __shared__ ushort Xl[264 * 64];   // 4 input rows x 66 px, 64 ci each
    __shared__ ushort Wl[128 * 64];   // 128 co x 64 ci
    __shared__ float  sB[128];

    const int tid = threadIdx.x;
    const int wv = tid >> 6, L = tid & 63, l31 = L & 31, q = L >> 5;
    const int b = blockIdx.y, oh0 = blockIdx.x * 2;
    const int m0 = (wv >> 1) * 64;   // co base for this wave
    const int rw = wv & 1;           // output row (0/1) for this wave

    f32x16 acc[2][2];
    #pragma unroll
    for (int i = 0; i < 2; ++i)
        #pragma unroll
        for (int j = 0; j < 2; ++j)
            #pragma unroll
            for (int r = 0; r < 16; ++r) acc[i][j][r] = 0.f;

    if (tid < 128) sB[tid] = bias[tid];

    // stage X: 264 pixels (4 rows x 66 cols), cols 64,65 zero-filled
    for (int p = tid; p < 264; p += 256) {
        const int r = p / 66, c = p - r * 66;
        ushort* dst = &Xl[p * 64];
        const int pm = p & 7;
        if (c < 64) {
            const uint4* src = (const uint4*)(xn + (((b * 64 + oh0 + r) * 64 + c) * 64));
            #pragma unroll
            for (int i = 0; i < 8; ++i) {
                uint4 v = src[i];
                *(uint4*)(dst + ((i ^ pm) * 8)) = v;
            }
        } else {
            const uint4 z = {0u, 0u, 0u, 0u};
            #pragma unroll
            for (int i = 0; i < 8; ++i) *(uint4*)(dst + ((i ^ pm) * 8)) = z;
        }
    }

    // W staging assignment: thread -> (co, half of ci)
    const int wco = tid >> 1, wch0 = (tid & 1) * 4;   // chunk base (each chunk = 8 ci)
    const int pmW = wco & 7;
    // prefetch kk=0
    uint4 wr[4];
    {
        const uint4* src = (const uint4*)(wt + wco * 64 + wch0 * 8);
        #pragma unroll
        for (int i = 0; i < 4; ++i) wr[i] = src[i];
    }

    const int pmA = l31 & 7;
    int offA[4];
    #pragma unroll
    for (int s = 0; s < 4; ++s) offA[s] = ((2 * s + q) ^ pmA) * 8;

    const ushort* aP0 = Wl + (m0 + l31) * 64;
    const ushort* aP1 = aP0 + 32 * 64;

    #pragma unroll
    for (int kk = 0; kk < 9; ++kk) {
        const int kr = kk / 3, kc = kk - kr * 3;
        __syncthreads();
        #pragma unroll
        for (int i = 0; i < 4; ++i)
            *(uint4*)(&Wl[wco * 64 + (((wch0 + i) ^ pmW) * 8)]) = wr[i];
        if (kk < 8) {
            const uint4* src = (const uint4*)(wt + (kk + 1) * 8192 + wco * 64 + wch0 * 8);
            #pragma unroll
            for (int i = 0; i < 4; ++i) wr[i] = src[i];
        }
        __syncthreads();

        const int pB = (rw + kr) * 66 + kc + l31;
        const int pmB = pB & 7;
        const ushort* bP0 = Xl + pB * 64;
        const ushort* bP1 = bP0 + 32 * 64;

        #pragma unroll
        for (int s = 0; s < 4; ++s) {
            const int oA = offA[s];
            const int oB = ((2 * s + q) ^ pmB) * 8;
            short8x a0 = *(const short8x*)(aP0 + oA);
            short8x a1 = *(const short8x*)(aP1 + oA);
            short8x b0 = *(const short8x*)(bP0 + oB);
            short8x b1 = *(const short8x*)(bP1 + oB);
            acc[0][0] = __builtin_amdgcn_mfma_f32_32x32x16_bf16(a0, b0, acc[0][0], 0, 0, 0);
            acc[0][1] = __builtin_amdgcn_mfma_f32_32x32x16_bf16(a0, b1, acc[0][1], 0, 0, 0);
            acc[1][0] = __builtin_amdgcn_mfma_f32_32x32x16_bf16(a1, b0, acc[1][0], 0, 0, 0);
            acc[1][1] = __builtin_amdgcn_mfma_f32_32x32x16_bf16(a1, b1, acc[1][1], 0, 0, 0);
        }
    }

    // epilogue: D row = co, D col = pixel -> coalesced dword stores
    const int oh = oh0 + rw;
    #pragma unroll
    for (int ti = 0; ti < 2; ++ti)
        #pragma unroll
        for (int tj = 0; tj < 2; ++tj) {
            const int col = tj * 32 + l31;
            if (col < OW) {
                #pragma unroll
                for (int reg = 0; reg < 16; ++reg) {
                    const int co = m0 + ti * 32 + 4 * q + (reg & 3) + 8 * (reg >> 2);
                    out[((b * CO + co) * OH + oh) * OW + col] = acc[ti][tj][reg] + sB[co];
                }
            }
        }
}

extern "C" void kernel_launch(void* const* d_in, const int* in_sizes, int n_in,
                              void* d_out, int out_size, void* d_ws, size_t ws_size,
                              hipStream_t stream) {
    const float* x    = (const float*)d_in[0];
    const float* wgt  = (const float*)d_in[1];
    const float* bias = (const float*)d_in[2];
    float* out = (float*)d_out;

    ushort* xn = (ushort*)d_ws;                          // 64*64*64*64 bf16 = 33.55 MB
    ushort* wt = (ushort*)((char*)d_ws + 33554432);      // 9*128*64 bf16 = 147 KB

    xpose<<<dim3(64, 64), 256, 0, stream>>>(x, xn);
    wprep<<<dim3(288), 256, 0, stream>>>(wgt, wt);
    conv_mfma<<<dim3(31, 64), 256, 0, stream>>>(xn, wt, bias, out);
}

// Round 3
// 255.496 us; speedup vs baseline: 2.9392x; 1.1351x over previous
//
#include <hip/hip_runtime.h>

#define CI 64
#define CO 128
#define HH 64
#define WW 64
#define OH 62
#define OW 62

typedef __attribute__((ext_vector_type(8))) short short8x;
typedef __attribute__((ext_vector_type(16))) float f32x16;

__device__ __forceinline__ ushort bf16rne(float f) {
    unsigned u = __builtin_bit_cast(unsigned, f);
    u += 0x7fffu + ((u >> 16) & 1u);
    return (ushort)(u >> 16);
}

// ---- tiny prepass: W OIHW fp32 -> [tap][co][ci] bf16 (147 KB, L2-resident) ----
__global__ __launch_bounds__(256)
void wprep(const float* __restrict__ w, ushort* __restrict__ wt) {
    const int idx = blockIdx.x * 256 + threadIdx.x;   // 73728 total
    const int kk = idx >> 13;
    const int rem = idx & 8191;
    const int co = rem >> 6, ci = rem & 63;
    wt[idx] = bf16rne(w[(co * 64 + ci) * 9 + kk]);
}

// ---- fused main: fp32 NCHW in, implicit GEMM 128co x (2 rows x 64 cols) per block ----
// LDS X tile [px][ci] bf16, chunk-XOR swizzle: chunk i of row px stored at (i ^ (px&7)).
// Weights: global->register A fragments, double-buffered per tap. ONE barrier total.
__global__ __launch_bounds__(256, 2)
void conv_fused(const float* __restrict__ x, const ushort* __restrict__ wt,
                const float* __restrict__ bias, float* __restrict__ out) {
    __shared__ ushort Xl[264 * 64];   // 4 input rows x 66 px, 64 ci each (33.8 KB)
    __shared__ float  sB[128];

    const int tid = threadIdx.x;
    const int wv = tid >> 6, L = tid & 63, l31 = L & 31, q = L >> 5;
    const int b = blockIdx.y, oh0 = blockIdx.x * 2;
    const int m0 = (wv >> 1) * 64;   // co base for this wave (64 couts)
    const int rw = wv & 1;           // output row (0/1) for this wave

    if (tid < 128) sB[tid] = bias[tid];

    // ---- stage X: read fp32 rows coalesced, cvt to bf16, b128 scatter into LDS ----
    for (int pxi = tid; pxi < 264; pxi += 256) {
        const int r = pxi / 66, cpos = pxi - r * 66;
        const int ih = oh0 + r;                       // oh0 max 60 -> ih max 63, in range
        const bool valid = cpos < 64;                 // cols 64,65 zero-filled
        const float* xcol = x + (((size_t)b * CI) * HH + ih) * WW + cpos;
        ushort* dst = &Xl[pxi * 64];
        const int pm = pxi & 7;
        #pragma unroll
        for (int c = 0; c < 8; ++c) {                 // ci chunk of 8
            ushort tmp[8];
            #pragma unroll
            for (int j = 0; j < 8; ++j) {
                float v = valid ? xcol[(c * 8 + j) * (HH * WW)] : 0.f;
                tmp[j] = bf16rne(v);
            }
            *(uint4*)(dst + ((c ^ pm) * 8)) = *(const uint4*)tmp;
        }
    }

    // ---- prefetch tap-0 weights into registers ----
    // A frag (verified layout): lane holds A[m=l31][k=q*8+j]; co = m0 + h*32 + l31
    short8x wbuf[2][8];   // [dbuf][h*4+s]
    const ushort* wbase = wt + (m0 + l31) * 64 + q * 8;
    #pragma unroll
    for (int h = 0; h < 2; ++h)
        #pragma unroll
        for (int s = 0; s < 4; ++s)
            wbuf[0][h * 4 + s] = *(const short8x*)(wbase + h * 2048 + s * 16);

    f32x16 acc[2][2];
    #pragma unroll
    for (int i = 0; i < 2; ++i)
        #pragma unroll
        for (int j = 0; j < 2; ++j)
            #pragma unroll
            for (int r = 0; r < 16; ++r) acc[i][j][r] = 0.f;

    __syncthreads();   // the only barrier in the kernel

    #pragma unroll
    for (int kk = 0; kk < 9; ++kk) {
        const short8x* wf = wbuf[kk & 1];
        if (kk < 8) {   // prefetch next tap while this tap computes
            const ushort* nb = wbase + (kk + 1) * 8192;
            #pragma unroll
            for (int h = 0; h < 2; ++h)
                #pragma unroll
                for (int s = 0; s < 4; ++s)
                    wbuf[(kk + 1) & 1][h * 4 + s] = *(const short8x*)(nb + h * 2048 + s * 16);
        }
        const int kr = kk / 3, kc = kk - kr * 3;
        const int pxb = (rw + kr) * 66 + kc + l31;
        const ushort* bb0 = Xl + pxb * 64;
        const int f0 = pxb & 7;                        // (pxb+32)&7 == f0
        #pragma unroll
        for (int s = 0; s < 4; ++s) {
            const int cch = s * 2 + q;
            short8x b0 = *(const short8x*)(bb0 + ((cch ^ f0) * 8));
            short8x b1 = *(const short8x*)(bb0 + 32 * 64 + ((cch ^ f0) * 8));
            acc[0][0] = __builtin_amdgcn_mfma_f32_32x32x16_bf16(wf[s],     b0, acc[0][0], 0, 0, 0);
            acc[0][1] = __builtin_amdgcn_mfma_f32_32x32x16_bf16(wf[s],     b1, acc[0][1], 0, 0, 0);
            acc[1][0] = __builtin_amdgcn_mfma_f32_32x32x16_bf16(wf[4 + s], b0, acc[1][0], 0, 0, 0);
            acc[1][1] = __builtin_amdgcn_mfma_f32_32x32x16_bf16(wf[4 + s], b1, acc[1][1], 0, 0, 0);
        }
    }

    // ---- epilogue: D row = co, D col = pixel -> coalesced dword stores ----
    const int oh = oh0 + rw;
    #pragma unroll
    for (int ti = 0; ti < 2; ++ti)
        #pragma unroll
        for (int tj = 0; tj < 2; ++tj) {
            const int col = tj * 32 + l31;
            if (col < OW) {
                #pragma unroll
                for (int reg = 0; reg < 16; ++reg) {
                    const int co = m0 + ti * 32 + 4 * q + (reg & 3) + 8 * (reg >> 2);
                    out[(((size_t)b * CO + co) * OH + oh) * OW + col] = acc[ti][tj][reg] + sB[co];
                }
            }
        }
}

extern "C" void kernel_launch(void* const* d_in, const int* in_sizes, int n_in,
                              void* d_out, int out_size, void* d_ws, size_t ws_size,
                              hipStream_t stream) {
    const float* x    = (const float*)d_in[0];
    const float* wgt  = (const float*)d_in[1];
    const float* bias = (const float*)d_in[2];
    float* out = (float*)d_out;

    ushort* wt = (ushort*)d_ws;   // 9*128*64 bf16 = 147 KB

    wprep<<<dim3(288), 256, 0, stream>>>(wgt, wt);
    conv_fused<<<dim3(31, 64), 256, 0, stream>>>(x, wt, bias, out);
}